// Round 7
// baseline (1577.243 us; speedup 1.0000x reference)
//
#include <hip/hip_runtime.h>
#include <math.h>

#define NC_   100000
#define ND_   100000
#define NN_   100000   // == NC_ == ND_
#define E_CNT 500000
#define L_CNT 100000
#define NH_   4
#define HD_   32
#define WCAT_SZ (129 * 384)

__device__ __forceinline__ float gelu_f(float x) {
    const float c0 = 0.7978845608028654f; // sqrt(2/pi)
    float x3 = x * x * x;
    return 0.5f * x * (1.0f + tanhf(c0 * (x + 0.044715f * x3)));
}

// ======================= CSR build (both relations fused, grid.y = r) ==========
__global__ __launch_bounds__(256) void fill0_int(int* __restrict__ p, int n) {
    int i = blockIdx.x * 256 + threadIdx.x;
    if (i < n) p[i] = 0;
}

__global__ __launch_bounds__(256) void count_dst(const int* __restrict__ dstA,
                                                 const int* __restrict__ dstB,
                                                 int* __restrict__ cnt) {
    int r = blockIdx.y;
    const int* dst = r ? dstB : dstA;
    int e = blockIdx.x * 256 + threadIdx.x;
    if (e < E_CNT) atomicAdd(&cnt[r * NN_ + dst[e]], 1);
}

__global__ __launch_bounds__(256) void scan_a(const int* __restrict__ cnt,
                                              int* __restrict__ excl,
                                              int* __restrict__ partials) {
    __shared__ int sd[256];
    int r = blockIdx.y;
    cnt += r * NN_; excl += r * (NN_ + 1); partials += r * 128;
    int b = blockIdx.x, t = threadIdx.x;
    int base = b * 1024 + t * 4;
    int v0 = (base + 0 < NN_) ? cnt[base + 0] : 0;
    int v1 = (base + 1 < NN_) ? cnt[base + 1] : 0;
    int v2 = (base + 2 < NN_) ? cnt[base + 2] : 0;
    int v3 = (base + 3 < NN_) ? cnt[base + 3] : 0;
    int tsum = v0 + v1 + v2 + v3;
    sd[t] = tsum; __syncthreads();
    for (int off = 1; off < 256; off <<= 1) {
        int x = (t >= off) ? sd[t - off] : 0;
        __syncthreads();
        sd[t] += x;
        __syncthreads();
    }
    int excl_t = sd[t] - tsum;
    if (t == 255) partials[b] = sd[t];
    int q = excl_t;
    if (base + 0 < NN_) excl[base + 0] = q; q += v0;
    if (base + 1 < NN_) excl[base + 1] = q; q += v1;
    if (base + 2 < NN_) excl[base + 2] = q; q += v2;
    if (base + 3 < NN_) excl[base + 3] = q;
}

__global__ __launch_bounds__(128) void scan_b(int* __restrict__ partials) {
    __shared__ int sd[128];
    partials += blockIdx.x * 128;
    int t = threadIdx.x;
    int orig = (t < 98) ? partials[t] : 0;
    sd[t] = orig; __syncthreads();
    for (int off = 1; off < 128; off <<= 1) {
        int x = (t >= off) ? sd[t - off] : 0;
        __syncthreads();
        sd[t] += x;
        __syncthreads();
    }
    if (t < 98) partials[t] = sd[t] - orig;
}

__global__ __launch_bounds__(256) void scan_c(int* __restrict__ row_ptr,
                                              const int* __restrict__ partials,
                                              int* __restrict__ cursor) {
    int r = blockIdx.y;
    row_ptr += r * (NN_ + 1); partials += r * 128; cursor += r * NN_;
    int b = blockIdx.x, t = threadIdx.x;
    int base = b * 1024 + t * 4;
    int add = partials[b];
    #pragma unroll
    for (int j = 0; j < 4; j++) {
        int i = base + j;
        if (i < NN_) { int v = row_ptr[i] + add; row_ptr[i] = v; cursor[i] = v; }
    }
    if (b == 0 && t == 0) row_ptr[NN_] = E_CNT;
}

__global__ __launch_bounds__(256) void scatter_edges(const int* __restrict__ srcA,
                                                     const int* __restrict__ dstA,
                                                     const int* __restrict__ srcB,
                                                     const int* __restrict__ dstB,
                                                     int* __restrict__ cursor,
                                                     int* __restrict__ srcs) {
    int r = blockIdx.y;
    const int* src = r ? srcB : srcA;
    const int* dst = r ? dstB : dstA;
    cursor += r * NN_; srcs += r * E_CNT;
    int e = blockIdx.x * 256 + threadIdx.x;
    if (e >= E_CNT) return;
    int pos = atomicAdd(&cursor[dst[e]], 1);
    srcs[pos] = src[e];
}

// ======================= weight fusion (both layers in one launch) ==============
__global__ void fuse_weights(const float* __restrict__ qW, const float* __restrict__ qb,
                             const float* __restrict__ kW, const float* __restrict__ kb,
                             const float* __restrict__ vW, const float* __restrict__ vb,
                             const float* __restrict__ arel, const float* __restrict__ mrel,
                             float* __restrict__ WcatAll)
{
    int i  = blockIdx.x;   // 0..128 (128 == bias row)
    int t  = blockIdx.y;
    int lyr = blockIdx.z;
    int oc = threadIdx.x;  // 0..383
    int lt = lyr * 2 + t;
    float* Wcat = WcatAll + (size_t)lt * WCAT_SZ;
    float val;
    if (oc < 128) {
        val = (i < 128) ? qW[(size_t)(lt * 128 + i) * 128 + oc] : qb[lt * 128 + oc];
    } else {
        int which = (oc >= 256);
        int cc = oc - (which ? 256 : 128);
        int h = cc >> 5, e = cc & 31;
        const float* W = which ? vW : kW;
        const float* b = which ? vb : kb;
        const float* R = (which ? mrel : arel) + (size_t)(lt * NH_ + h) * HD_ * HD_ + e;
        float s = 0.f;
        if (i < 128) {
            const float* wrow = W + (size_t)(lt * 128 + i) * 128 + h * 32;
            #pragma unroll
            for (int d2 = 0; d2 < 32; d2++) s += wrow[d2] * R[d2 * 32];
        } else {
            const float* brow = b + lt * 128 + h * 32;
            #pragma unroll
            for (int d2 = 0; d2 < 32; d2++) s += brow[d2] * R[d2 * 32];
        }
        val = s;
    }
    Wcat[(size_t)((i < 128) ? i : 128) * 384 + oc] = val;
}

// ======================= fp32 tiled GEMM v4 =======================
// C[M,N] = A[M,128] @ B[128,N] + bias; tile 256 x TN, BK=16, 256 threads,
// 16 x (TN/16) register blocking. Software-pipelined staging, conflict-free LDS.
// POST: C = relu(g*v + (1-g)*resid) (resid may alias C).
// Dual-problem support via ySplit (blocks with blockIdx.y >= ySplit use *2 ptrs).
template<int TN, int POST>
__global__ __launch_bounds__(256, 2)
void gemm3(const float* __restrict__ A, int lda,
           const float* __restrict__ B, int ldb,
           const float* __restrict__ bias,
           float* __restrict__ C, int ldc,
           int M,
           const float* __restrict__ resid,
           const float* __restrict__ skipv,
           int ySplit,
           const float* __restrict__ A2, const float* __restrict__ B2,
           const float* __restrict__ bias2, float* __restrict__ C2, int ldc2)
{
    constexpr int TC = TN / 16;         // cols per thread (8 or 4)
    __shared__ float As[16][260];       // [k][m], 256 + pad
    __shared__ float Bs[16][TN + 4];    // [k][n]
    int by = blockIdx.y;
    if (ySplit >= 0 && by >= ySplit) {
        A = A2; B = B2; bias = bias2; C = C2; ldc = ldc2; by -= ySplit;
    }
    int tid = threadIdx.x;
    int tx = tid & 15, ty = tid >> 4;
    int bm = blockIdx.x * 256;
    int bn = by * TN;
    float acc[16][TC];
    #pragma unroll
    for (int i = 0; i < 16; i++)
        #pragma unroll
        for (int j = 0; j < TC; j++) acc[i][j] = 0.f;

    // A staging: thread covers rows m1 and m1+128, 8 k-consecutive floats each
    int m1   = tid >> 1;                // 0..127
    int koff = (tid & 1) * 8;           // 0 or 8
    int r1 = bm + m1, r2 = r1 + 128;
    bool v1 = r1 < M, v2 = r2 < M;
    const float* ap1 = A + (size_t)r1 * lda + koff;
    const float* ap2 = A + (size_t)r2 * lda + koff;
    // B staging
    int k_b = tid >> 4;                 // 0..15
    int txs = tid & 15;
    const float* bptr = B + (size_t)k_b * ldb + bn + txs * 4;

    float4 z4 = make_float4(0.f, 0.f, 0.f, 0.f);
    float4 a10 = z4, a11 = z4, a20 = z4, a21 = z4, b0 = z4, b1 = z4;
    if (v1) { a10 = *(const float4*)(ap1); a11 = *(const float4*)(ap1 + 4); }
    if (v2) { a20 = *(const float4*)(ap2); a21 = *(const float4*)(ap2 + 4); }
    b0 = *(const float4*)(bptr);
    if (TC == 8) b1 = *(const float4*)(bptr + 64);

    for (int k0 = 0; k0 < 128; k0 += 16) {
        __syncthreads();
        As[koff + 0][m1] = a10.x; As[koff + 1][m1] = a10.y;
        As[koff + 2][m1] = a10.z; As[koff + 3][m1] = a10.w;
        As[koff + 4][m1] = a11.x; As[koff + 5][m1] = a11.y;
        As[koff + 6][m1] = a11.z; As[koff + 7][m1] = a11.w;
        As[koff + 0][m1 + 128] = a20.x; As[koff + 1][m1 + 128] = a20.y;
        As[koff + 2][m1 + 128] = a20.z; As[koff + 3][m1 + 128] = a20.w;
        As[koff + 4][m1 + 128] = a21.x; As[koff + 5][m1 + 128] = a21.y;
        As[koff + 6][m1 + 128] = a21.z; As[koff + 7][m1 + 128] = a21.w;
        *(float4*)&Bs[k_b][txs * 4] = b0;
        if (TC == 8) *(float4*)&Bs[k_b][64 + txs * 4] = b1;
        __syncthreads();
        // prefetch next slab (hidden behind the FMA block)
        if (k0 + 16 < 128) {
            if (v1) { a10 = *(const float4*)(ap1 + k0 + 16); a11 = *(const float4*)(ap1 + k0 + 20); }
            if (v2) { a20 = *(const float4*)(ap2 + k0 + 16); a21 = *(const float4*)(ap2 + k0 + 20); }
            b0 = *(const float4*)(bptr + (size_t)(k0 + 16) * ldb);
            if (TC == 8) b1 = *(const float4*)(bptr + (size_t)(k0 + 16) * ldb + 64);
        }
        #pragma unroll
        for (int kk = 0; kk < 16; kk++) {
            float a[16], b[TC];
            *(float4*)&a[0]  = *(const float4*)&As[kk][ty * 16 + 0];
            *(float4*)&a[4]  = *(const float4*)&As[kk][ty * 16 + 4];
            *(float4*)&a[8]  = *(const float4*)&As[kk][ty * 16 + 8];
            *(float4*)&a[12] = *(const float4*)&As[kk][ty * 16 + 12];
            *(float4*)&b[0] = *(const float4*)&Bs[kk][tx * 4];
            if (TC == 8) *(float4*)&b[4] = *(const float4*)&Bs[kk][64 + tx * 4];
            #pragma unroll
            for (int i = 0; i < 16; i++)
                #pragma unroll
                for (int j = 0; j < TC; j++)
                    acc[i][j] += a[i] * b[j];
        }
    }

    float g = 0.f, omg = 0.f;
    if (POST) { float sv = skipv[0]; g = 1.0f / (1.0f + expf(-sv)); omg = 1.0f - g; }
    float bb[TC];
    #pragma unroll
    for (int j = 0; j < 4; j++) bb[j] = bias[bn + tx * 4 + j];
    if (TC == 8)
        #pragma unroll
        for (int j = 0; j < 4; j++) bb[4 + j] = bias[bn + 64 + tx * 4 + j];
    #pragma unroll
    for (int i = 0; i < 16; i++) {
        int m = bm + ty * 16 + i;
        if (m >= M) continue;
        #pragma unroll
        for (int half = 0; half < TC / 4; half++) {
            int coff = bn + half * 64 + tx * 4;
            float* crow = C + (size_t)m * ldc + coff;
            float4 v;
            v.x = acc[i][half * 4 + 0] + bb[half * 4 + 0];
            v.y = acc[i][half * 4 + 1] + bb[half * 4 + 1];
            v.z = acc[i][half * 4 + 2] + bb[half * 4 + 2];
            v.w = acc[i][half * 4 + 3] + bb[half * 4 + 3];
            if (POST) {
                float4 r = *(const float4*)(resid + (size_t)m * ldc + coff);
                v.x = fmaxf(g * v.x + omg * r.x, 0.f);
                v.y = fmaxf(g * v.y + omg * r.y, 0.f);
                v.z = fmaxf(g * v.z + omg * r.z, 0.f);
                v.w = fmaxf(g * v.w + omg * r.w, 0.f);
            }
            *(float4*)crow = v;
        }
    }
}

// ======================= fused attention gather (4 edges in flight) ============
// One wave per dst node; group = lane>>4 (edge slot), 16 lanes/edge, 8 dims/lane.
// head h = (lane&15)>>2. Online softmax; hierarchical merge; output is
// gelu(attn_out) (feeds the epilogue GEMM directly).
__global__ __launch_bounds__(256)
void attn_gather(const int* __restrict__ row_ptr, const int* __restrict__ srcs,
                 float* __restrict__ qo, const float* __restrict__ kv,
                 const float* __restrict__ prel, int ndst)
{
    int wave = (blockIdx.x * 256 + threadIdx.x) >> 6;
    int lane = threadIdx.x & 63;
    if (wave >= ndst) return;
    int d = wave;
    int gl = lane & 15;
    int group = lane >> 4;
    int h = gl >> 2;
    float pr = prel[h] * 0.17677669529663687f;  // prel / sqrt(32)
    int beg = row_ptr[d], end = row_ptr[d + 1];
    const float* qrow = qo + (size_t)d * 128 + gl * 8;
    float4 q0 = *(const float4*)(qrow);
    float4 q1 = *(const float4*)(qrow + 4);
    float m = -1.0e30f, l = 0.f;
    float4 acc0 = make_float4(0.f,0.f,0.f,0.f), acc1 = acc0;
    int nt = (end - beg + 3) >> 2;
    for (int t = 0; t < nt; t++) {
        int i = beg + (t << 2) + group;
        if (i < end) {
            int s = srcs[i];
            const float* row = kv + (size_t)s * 256 + gl * 8;
            float4 k0 = *(const float4*)(row);
            float4 k1 = *(const float4*)(row + 4);
            float4 v0 = *(const float4*)(row + 128);
            float4 v1 = *(const float4*)(row + 132);
            float part = q0.x*k0.x + q0.y*k0.y + q0.z*k0.z + q0.w*k0.w
                       + q1.x*k1.x + q1.y*k1.y + q1.z*k1.z + q1.w*k1.w;
            part += __shfl_xor(part, 1);
            part += __shfl_xor(part, 2);
            float a = part * pr;
            float mn = fmaxf(m, a);
            float scale = expf(m - mn);
            float p = expf(a - mn);
            l = l * scale + p;
            acc0.x = acc0.x * scale + p * v0.x;
            acc0.y = acc0.y * scale + p * v0.y;
            acc0.z = acc0.z * scale + p * v0.z;
            acc0.w = acc0.w * scale + p * v0.w;
            acc1.x = acc1.x * scale + p * v1.x;
            acc1.y = acc1.y * scale + p * v1.y;
            acc1.z = acc1.z * scale + p * v1.z;
            acc1.w = acc1.w * scale + p * v1.w;
            m = mn;
        }
    }
    #pragma unroll
    for (int mask = 16; mask <= 32; mask <<= 1) {
        float m_o = __shfl_xor(m, mask);
        float l_o = __shfl_xor(l, mask);
        float4 a0o, a1o;
        a0o.x = __shfl_xor(acc0.x, mask); a0o.y = __shfl_xor(acc0.y, mask);
        a0o.z = __shfl_xor(acc0.z, mask); a0o.w = __shfl_xor(acc0.w, mask);
        a1o.x = __shfl_xor(acc1.x, mask); a1o.y = __shfl_xor(acc1.y, mask);
        a1o.z = __shfl_xor(acc1.z, mask); a1o.w = __shfl_xor(acc1.w, mask);
        float mn = fmaxf(m, m_o);
        float s0 = expf(m - mn), s1 = expf(m_o - mn);
        l = l * s0 + l_o * s1;
        acc0.x = acc0.x * s0 + a0o.x * s1; acc0.y = acc0.y * s0 + a0o.y * s1;
        acc0.z = acc0.z * s0 + a0o.z * s1; acc0.w = acc0.w * s0 + a0o.w * s1;
        acc1.x = acc1.x * s0 + a1o.x * s1; acc1.y = acc1.y * s0 + a1o.y * s1;
        acc1.z = acc1.z * s0 + a1o.z * s1; acc1.w = acc1.w * s0 + a1o.w * s1;
        m = mn;
    }
    float inv = (beg == end) ? 0.f : 1.f / (l + 1e-16f);
    if (group == 0) {
        float* orow = qo + (size_t)d * 128 + gl * 8;
        float4 o0, o1;
        o0.x = gelu_f(acc0.x * inv); o0.y = gelu_f(acc0.y * inv);
        o0.z = gelu_f(acc0.z * inv); o0.w = gelu_f(acc0.w * inv);
        o1.x = gelu_f(acc1.x * inv); o1.y = gelu_f(acc1.y * inv);
        o1.z = gelu_f(acc1.z * inv); o1.w = gelu_f(acc1.w * inv);
        *(float4*)(orow)     = o0;
        *(float4*)(orow + 4) = o1;
    }
}

// ======================= final scoring =======================
__global__ __launch_bounds__(256)
void score_pairs(const int* __restrict__ ic, const int* __restrict__ id,
                 const float* __restrict__ zC, const float* __restrict__ zD,
                 float* __restrict__ out)
{
    int gid = blockIdx.x * 256 + threadIdx.x;
    int p = gid >> 4, lane = gid & 15;
    if (p >= L_CNT) return;
    int c = ic[p], d = id[p];
    float4 a = *(const float4*)(zC + (size_t)c * 64 + lane * 4);
    float4 b = *(const float4*)(zD + (size_t)d * 64 + lane * 4);
    float s = a.x * b.x + a.y * b.y + a.z * b.z + a.w * b.w;
    s += __shfl_down(s, 8, 16);
    s += __shfl_down(s, 4, 16);
    s += __shfl_down(s, 2, 16);
    s += __shfl_down(s, 1, 16);
    if (lane == 0) out[p] = fminf(10.0f, fmaxf(-10.0f, s));
}

extern "C" void kernel_launch(void* const* d_in, const int* in_sizes, int n_in,
                              void* d_out, int out_size, void* d_ws, size_t ws_size,
                              hipStream_t stream)
{
    // Persistent node states live in the emb input buffers (harness restores
    // d_in from pristine copies before every timed launch).
    float* xC = (float*)d_in[0];
    float* xD = (float*)d_in[1];
    const float* kW   = (const float*)d_in[2];
    const float* kb   = (const float*)d_in[3];
    const float* qW   = (const float*)d_in[4];
    const float* qb   = (const float*)d_in[5];
    const float* vW   = (const float*)d_in[6];
    const float* vb   = (const float*)d_in[7];
    const float* aW   = (const float*)d_in[8];
    const float* ab   = (const float*)d_in[9];
    const float* skip = (const float*)d_in[10];
    const float* arel = (const float*)d_in[11];
    const float* mrel = (const float*)d_in[12];
    const float* prel = (const float*)d_in[13];
    const float* outW = (const float*)d_in[14];
    const float* outb = (const float*)d_in[15];
    const int* ei_cd  = (const int*)d_in[16];
    const int* ei_dc  = (const int*)d_in[17];
    const int* eli    = (const int*)d_in[18];

    // ---- workspace: ~38.6M floats + ~1.6M ints ≈ 161 MB ----
    float* ws = (float*)d_ws;
    size_t off = 0;
    float* kv    = ws + off; off += (size_t)NN_ * 256;   // 25.6M  src [k|v]
    float* qo    = ws + off; off += (size_t)NN_ * 128;   // 12.8M  dst q -> gelu(attn out)
    float* Wcat  = ws + off; off += (size_t)4 * WCAT_SZ;
    int* iws = (int*)(ws + off);
    size_t ioff = 0;
    int* rp      = iws + ioff; ioff += 2 * (NN_ + 1);    // row_ptr planes [r]
    int* srcsA   = iws + ioff; ioff += 2 * E_CNT;        // src planes [r]
    int* cnt     = iws + ioff; ioff += 2 * NN_;
    int* cursor  = iws + ioff; ioff += 2 * NN_;
    int* partial = iws + ioff; ioff += 256;
    float* zC = kv;                                      // reuse after edge phases
    float* zD = kv + (size_t)NN_ * 128;

    const int gridM = (NN_ + 255) / 256;          // 391
    const int gE    = (E_CNT + 255) / 256;
    const int gN2   = (2 * NN_ + 255) / 256;
    const int gScan = 98;
    const int gGath = (NN_ + 3) / 4;              // 4 waves/block

    // ---- build CSR for both relations (fused, grid.y = r) ----
    fill0_int<<<gN2, 256, 0, stream>>>(cnt, 2 * NN_);
    count_dst<<<dim3(gE, 2), 256, 0, stream>>>(ei_cd + E_CNT, ei_dc + E_CNT, cnt);
    scan_a<<<dim3(gScan, 2), 256, 0, stream>>>(cnt, rp, partial);
    scan_b<<<2, 128, 0, stream>>>(partial);
    scan_c<<<dim3(gScan, 2), 256, 0, stream>>>(rp, partial, cursor);
    scatter_edges<<<dim3(gE, 2), 256, 0, stream>>>(ei_cd, ei_cd + E_CNT,
                                                   ei_dc, ei_dc + E_CNT, cursor, srcsA);
    int* rp_cd   = rp;
    int* rp_dc   = rp + (NN_ + 1);
    int* srcs_cd = srcsA;
    int* srcs_dc = srcsA + E_CNT;

    // ---- all weight fusion in one launch ----
    fuse_weights<<<dim3(129, 2, 2), 384, 0, stream>>>(qW, qb, kW, kb, vW, vb,
                                                      arel, mrel, Wcat);

    for (int l = 0; l < 2; l++) {
        const float* aWl = aW + (size_t)l * 2 * 128 * 128;
        const float* abl = ab + (size_t)l * 2 * 128;
        float* WcC = Wcat + (size_t)(l * 2 + 0) * WCAT_SZ;
        float* WcD = Wcat + (size_t)(l * 2 + 1) * WCAT_SZ;

        // ---- relation 0: C -> D ----  (dual: kvC y0-1, qD y2)
        gemm3<128, 0><<<dim3(gridM, 3), 256, 0, stream>>>(
            xC, 128, WcC + 128, 384, WcC + 128 * 384 + 128, kv, 256, NC_, nullptr, nullptr,
            2, xD, WcD, WcD + 128 * 384, qo, 128);
        attn_gather<<<gGath, 256, 0, stream>>>(rp_cd, srcs_cd, qo, kv,
                                               prel + (l * 2 + 0) * 4, ND_);  // gelu(outD) in qo

        // kvD from OLD xD (before epilogue D overwrites it)
        gemm3<128, 0><<<dim3(gridM, 2), 256, 0, stream>>>(
            xD, 128, WcD + 128, 384, WcD + 128 * 384 + 128, kv, 256, ND_, nullptr, nullptr,
            -1, nullptr, nullptr, nullptr, nullptr, 0);

        // epilogue D: xD = relu(g*(gelu(outD)@aW_D+ab_D) + (1-g)*xD)
        gemm3<128, 1><<<dim3(gridM, 1), 256, 0, stream>>>(
            qo, 128, aWl + 128 * 128, 128, abl + 128, xD, 128, ND_, xD, skip + l * 2 + 1,
            -1, nullptr, nullptr, nullptr, nullptr, 0);

        // ---- relation 1: D -> C ----
        gemm3<128, 0><<<dim3(gridM, 1), 256, 0, stream>>>(     // qC (old xC)
            xC, 128, WcC, 384, WcC + 128 * 384, qo, 128, NC_, nullptr, nullptr,
            -1, nullptr, nullptr, nullptr, nullptr, 0);
        attn_gather<<<gGath, 256, 0, stream>>>(rp_dc, srcs_dc, qo, kv,
                                               prel + (l * 2 + 1) * 4, NC_);  // gelu(outC) in qo

        // epilogue C
        gemm3<128, 1><<<dim3(gridM, 1), 256, 0, stream>>>(
            qo, 128, aWl, 128, abl, xC, 128, NC_, xC, skip + l * 2 + 0,
            -1, nullptr, nullptr, nullptr, nullptr, 0);
    }

    // final projections z = x @ outW + outb  ([N,128] @ [128,64]), both types dual
    gemm3<64, 0><<<dim3(gridM, 2), 256, 0, stream>>>(
        xC, 128, outW, 64, outb, zC, 64, NC_, nullptr, nullptr,
        1, xD, outW + 128 * 64, outb + 64, zD, 64);

    score_pairs<<<(L_CNT * 16 + 255) / 256, 256, 0, stream>>>(
        eli, eli + L_CNT, zC, zD, (float*)d_out);
}

// Round 8
// 1445.193 us; speedup vs baseline: 1.0914x; 1.0914x over previous
//
#include <hip/hip_runtime.h>
#include <math.h>

#define NC_   100000
#define ND_   100000
#define NN_   100000   // == NC_ == ND_
#define E_CNT 500000
#define L_CNT 100000
#define NH_   4
#define HD_   32
#define WCAT_SZ (129 * 384)

__device__ __forceinline__ float gelu_f(float x) {
    const float c0 = 0.7978845608028654f; // sqrt(2/pi)
    float x3 = x * x * x;
    return 0.5f * x * (1.0f + tanhf(c0 * (x + 0.044715f * x3)));
}

// ======================= CSR build (both relations fused, grid.y = r) ==========
__global__ __launch_bounds__(256) void fill0_int(int* __restrict__ p, int n) {
    int i = blockIdx.x * 256 + threadIdx.x;
    if (i < n) p[i] = 0;
}

__global__ __launch_bounds__(256) void count_dst(const int* __restrict__ dstA,
                                                 const int* __restrict__ dstB,
                                                 int* __restrict__ cnt) {
    int r = blockIdx.y;
    const int* dst = r ? dstB : dstA;
    int e = blockIdx.x * 256 + threadIdx.x;
    if (e < E_CNT) atomicAdd(&cnt[r * NN_ + dst[e]], 1);
}

__global__ __launch_bounds__(256) void scan_a(const int* __restrict__ cnt,
                                              int* __restrict__ excl,
                                              int* __restrict__ partials) {
    __shared__ int sd[256];
    int r = blockIdx.y;
    cnt += r * NN_; excl += r * (NN_ + 1); partials += r * 128;
    int b = blockIdx.x, t = threadIdx.x;
    int base = b * 1024 + t * 4;
    int v0 = (base + 0 < NN_) ? cnt[base + 0] : 0;
    int v1 = (base + 1 < NN_) ? cnt[base + 1] : 0;
    int v2 = (base + 2 < NN_) ? cnt[base + 2] : 0;
    int v3 = (base + 3 < NN_) ? cnt[base + 3] : 0;
    int tsum = v0 + v1 + v2 + v3;
    sd[t] = tsum; __syncthreads();
    for (int off = 1; off < 256; off <<= 1) {
        int x = (t >= off) ? sd[t - off] : 0;
        __syncthreads();
        sd[t] += x;
        __syncthreads();
    }
    int excl_t = sd[t] - tsum;
    if (t == 255) partials[b] = sd[t];
    int q = excl_t;
    if (base + 0 < NN_) excl[base + 0] = q; q += v0;
    if (base + 1 < NN_) excl[base + 1] = q; q += v1;
    if (base + 2 < NN_) excl[base + 2] = q; q += v2;
    if (base + 3 < NN_) excl[base + 3] = q;
}

__global__ __launch_bounds__(128) void scan_b(int* __restrict__ partials) {
    __shared__ int sd[128];
    partials += blockIdx.x * 128;
    int t = threadIdx.x;
    int orig = (t < 98) ? partials[t] : 0;
    sd[t] = orig; __syncthreads();
    for (int off = 1; off < 128; off <<= 1) {
        int x = (t >= off) ? sd[t - off] : 0;
        __syncthreads();
        sd[t] += x;
        __syncthreads();
    }
    if (t < 98) partials[t] = sd[t] - orig;
}

__global__ __launch_bounds__(256) void scan_c(int* __restrict__ row_ptr,
                                              const int* __restrict__ partials,
                                              int* __restrict__ cursor) {
    int r = blockIdx.y;
    row_ptr += r * (NN_ + 1); partials += r * 128; cursor += r * NN_;
    int b = blockIdx.x, t = threadIdx.x;
    int base = b * 1024 + t * 4;
    int add = partials[b];
    #pragma unroll
    for (int j = 0; j < 4; j++) {
        int i = base + j;
        if (i < NN_) { int v = row_ptr[i] + add; row_ptr[i] = v; cursor[i] = v; }
    }
    if (b == 0 && t == 0) row_ptr[NN_] = E_CNT;
}

__global__ __launch_bounds__(256) void scatter_edges(const int* __restrict__ srcA,
                                                     const int* __restrict__ dstA,
                                                     const int* __restrict__ srcB,
                                                     const int* __restrict__ dstB,
                                                     int* __restrict__ cursor,
                                                     int* __restrict__ srcs) {
    int r = blockIdx.y;
    const int* src = r ? srcB : srcA;
    const int* dst = r ? dstB : dstA;
    cursor += r * NN_; srcs += r * E_CNT;
    int e = blockIdx.x * 256 + threadIdx.x;
    if (e >= E_CNT) return;
    int pos = atomicAdd(&cursor[dst[e]], 1);
    srcs[pos] = src[e];
}

// ======================= weight fusion (both layers in one launch) ==============
__global__ void fuse_weights(const float* __restrict__ qW, const float* __restrict__ qb,
                             const float* __restrict__ kW, const float* __restrict__ kb,
                             const float* __restrict__ vW, const float* __restrict__ vb,
                             const float* __restrict__ arel, const float* __restrict__ mrel,
                             float* __restrict__ WcatAll)
{
    int i  = blockIdx.x;   // 0..128 (128 == bias row)
    int t  = blockIdx.y;
    int lyr = blockIdx.z;
    int oc = threadIdx.x;  // 0..383
    int lt = lyr * 2 + t;
    float* Wcat = WcatAll + (size_t)lt * WCAT_SZ;
    float val;
    if (oc < 128) {
        val = (i < 128) ? qW[(size_t)(lt * 128 + i) * 128 + oc] : qb[lt * 128 + oc];
    } else {
        int which = (oc >= 256);
        int cc = oc - (which ? 256 : 128);
        int h = cc >> 5, e = cc & 31;
        const float* W = which ? vW : kW;
        const float* b = which ? vb : kb;
        const float* R = (which ? mrel : arel) + (size_t)(lt * NH_ + h) * HD_ * HD_ + e;
        float s = 0.f;
        if (i < 128) {
            const float* wrow = W + (size_t)(lt * 128 + i) * 128 + h * 32;
            #pragma unroll
            for (int d2 = 0; d2 < 32; d2++) s += wrow[d2] * R[d2 * 32];
        } else {
            const float* brow = b + lt * 128 + h * 32;
            #pragma unroll
            for (int d2 = 0; d2 < 32; d2++) s += brow[d2] * R[d2 * 32];
        }
        val = s;
    }
    Wcat[(size_t)((i < 128) ? i : 128) * 384 + oc] = val;
}

// ======================= fp32 tiled GEMM (128-row tile, double-buffered LDS) ====
// C[M,N] = A[M,128] @ B[128,N] + bias; tile 128 x TN, BK=16, 256 threads,
// 8 x (TN/16) register blocking. ONE barrier per K-slab (double-buffered LDS).
// POST: C = relu(g*v + (1-g)*resid) (resid may alias C).
// Dual-problem support via ySplit (blocks with blockIdx.y >= ySplit use *2 ptrs).
template<int TN, int POST>
__global__ __launch_bounds__(256)
void gemm2(const float* __restrict__ A, int lda,
           const float* __restrict__ B, int ldb,
           const float* __restrict__ bias,
           float* __restrict__ C, int ldc,
           int M,
           const float* __restrict__ resid,
           const float* __restrict__ skipv,
           int ySplit,
           const float* __restrict__ A2, const float* __restrict__ B2,
           const float* __restrict__ bias2, float* __restrict__ C2, int ldc2)
{
    constexpr int TC = TN / 16;         // cols per thread (8 or 4)
    __shared__ float As[2][16][132];    // [buf][k][m]
    __shared__ float Bs[2][16][TN + 4]; // [buf][k][n]
    int by = blockIdx.y;
    if (ySplit >= 0 && by >= ySplit) {
        A = A2; B = B2; bias = bias2; C = C2; ldc = ldc2; by -= ySplit;
    }
    int tid = threadIdx.x;
    int tx = tid & 15, ty = tid >> 4;
    int bm = blockIdx.x * 128;
    int bn = by * TN;
    float acc[8][TC];
    #pragma unroll
    for (int i = 0; i < 8; i++)
        #pragma unroll
        for (int j = 0; j < TC; j++) acc[i][j] = 0.f;

    // A staging: thread loads 8 k-consecutive floats of row m_a
    int m_a  = tid >> 1;                // 0..127
    int koff = (tid & 1) * 8;           // 0 or 8
    int arow = bm + m_a;
    bool avalid = arow < M;
    const float* aptr = A + (size_t)arow * lda + koff;
    // B staging: thread loads cols {txs*4..+3} (+ {64+txs*4..+3}) of row k_b
    int k_b = tid >> 4;                 // 0..15
    int txs = tid & 15;
    const float* bptr = B + (size_t)k_b * ldb + bn + txs * 4;

    // prologue: load K-slab 0 and stage into buffer 0
    float4 a0 = make_float4(0.f,0.f,0.f,0.f), a1 = a0, b0, b1;
    if (avalid) { a0 = *(const float4*)(aptr); a1 = *(const float4*)(aptr + 4); }
    b0 = *(const float4*)(bptr);
    if (TC == 8) b1 = *(const float4*)(bptr + 64);
    As[0][koff + 0][m_a] = a0.x; As[0][koff + 1][m_a] = a0.y;
    As[0][koff + 2][m_a] = a0.z; As[0][koff + 3][m_a] = a0.w;
    As[0][koff + 4][m_a] = a1.x; As[0][koff + 5][m_a] = a1.y;
    As[0][koff + 6][m_a] = a1.z; As[0][koff + 7][m_a] = a1.w;
    *(float4*)&Bs[0][k_b][txs * 4] = b0;
    if (TC == 8) *(float4*)&Bs[0][k_b][64 + txs * 4] = b1;
    __syncthreads();

    int ibuf = 0;
    for (int k0 = 0; k0 < 128; k0 += 16) {
        // prefetch next slab into registers (latency hidden behind FMA block)
        bool more = (k0 + 16) < 128;
        if (more) {
            if (avalid) {
                a0 = *(const float4*)(aptr + k0 + 16);
                a1 = *(const float4*)(aptr + k0 + 20);
            }
            b0 = *(const float4*)(bptr + (size_t)(k0 + 16) * ldb);
            if (TC == 8) b1 = *(const float4*)(bptr + (size_t)(k0 + 16) * ldb + 64);
        }
        #pragma unroll
        for (int kk = 0; kk < 16; kk++) {
            float a[8], b[TC];
            *(float4*)&a[0] = *(const float4*)&As[ibuf][kk][ty * 8];
            *(float4*)&a[4] = *(const float4*)&As[ibuf][kk][ty * 8 + 4];
            *(float4*)&b[0] = *(const float4*)&Bs[ibuf][kk][tx * 4];
            if (TC == 8) *(float4*)&b[4] = *(const float4*)&Bs[ibuf][kk][64 + tx * 4];
            #pragma unroll
            for (int i = 0; i < 8; i++)
                #pragma unroll
                for (int j = 0; j < TC; j++)
                    acc[i][j] += a[i] * b[j];
        }
        if (more) {
            int nb = ibuf ^ 1;   // write next slab into the other buffer
            As[nb][koff + 0][m_a] = a0.x; As[nb][koff + 1][m_a] = a0.y;
            As[nb][koff + 2][m_a] = a0.z; As[nb][koff + 3][m_a] = a0.w;
            As[nb][koff + 4][m_a] = a1.x; As[nb][koff + 5][m_a] = a1.y;
            As[nb][koff + 6][m_a] = a1.z; As[nb][koff + 7][m_a] = a1.w;
            *(float4*)&Bs[nb][k_b][txs * 4] = b0;
            if (TC == 8) *(float4*)&Bs[nb][k_b][64 + txs * 4] = b1;
            __syncthreads();
            ibuf = nb;
        }
    }

    float g = 0.f, omg = 0.f;
    if (POST) { float sv = skipv[0]; g = 1.0f / (1.0f + expf(-sv)); omg = 1.0f - g; }
    float bb[TC];
    #pragma unroll
    for (int j = 0; j < 4; j++) bb[j] = bias[bn + tx * 4 + j];
    if (TC == 8)
        #pragma unroll
        for (int j = 0; j < 4; j++) bb[4 + j] = bias[bn + 64 + tx * 4 + j];
    #pragma unroll
    for (int i = 0; i < 8; i++) {
        int m = bm + ty * 8 + i;
        if (m >= M) continue;
        #pragma unroll
        for (int half = 0; half < TC / 4; half++) {
            int coff = bn + half * 64 + tx * 4;
            float* crow = C + (size_t)m * ldc + coff;
            float4 v;
            v.x = acc[i][half * 4 + 0] + bb[half * 4 + 0];
            v.y = acc[i][half * 4 + 1] + bb[half * 4 + 1];
            v.z = acc[i][half * 4 + 2] + bb[half * 4 + 2];
            v.w = acc[i][half * 4 + 3] + bb[half * 4 + 3];
            if (POST) {
                float4 r = *(const float4*)(resid + (size_t)m * ldc + coff);
                v.x = fmaxf(g * v.x + omg * r.x, 0.f);
                v.y = fmaxf(g * v.y + omg * r.y, 0.f);
                v.z = fmaxf(g * v.z + omg * r.z, 0.f);
                v.w = fmaxf(g * v.w + omg * r.w, 0.f);
            }
            *(float4*)crow = v;
        }
    }
}

// ======================= fused attention gather (4 edges in flight) ============
// One wave per dst node; group = lane>>4 (edge slot), 16 lanes/edge, 8 dims/lane.
// head h = (lane&15)>>2. Online softmax; hierarchical merge; writes
// gelu(attn_out) (feeds the epilogue GEMM directly).
__global__ __launch_bounds__(256)
void attn_gather(const int* __restrict__ row_ptr, const int* __restrict__ srcs,
                 float* __restrict__ qo, const float* __restrict__ kv,
                 const float* __restrict__ prel, int ndst)
{
    int wave = (blockIdx.x * 256 + threadIdx.x) >> 6;
    int lane = threadIdx.x & 63;
    if (wave >= ndst) return;
    int d = wave;
    int gl = lane & 15;
    int group = lane >> 4;
    int h = gl >> 2;
    float pr = prel[h] * 0.17677669529663687f;  // prel / sqrt(32)
    int beg = row_ptr[d], end = row_ptr[d + 1];
    const float* qrow = qo + (size_t)d * 128 + gl * 8;
    float4 q0 = *(const float4*)(qrow);
    float4 q1 = *(const float4*)(qrow + 4);
    float m = -1.0e30f, l = 0.f;
    float4 acc0 = make_float4(0.f,0.f,0.f,0.f), acc1 = acc0;
    int nt = (end - beg + 3) >> 2;
    for (int t = 0; t < nt; t++) {
        int i = beg + (t << 2) + group;
        if (i < end) {
            int s = srcs[i];
            const float* row = kv + (size_t)s * 256 + gl * 8;
            float4 k0 = *(const float4*)(row);
            float4 k1 = *(const float4*)(row + 4);
            float4 v0 = *(const float4*)(row + 128);
            float4 v1 = *(const float4*)(row + 132);
            float part = q0.x*k0.x + q0.y*k0.y + q0.z*k0.z + q0.w*k0.w
                       + q1.x*k1.x + q1.y*k1.y + q1.z*k1.z + q1.w*k1.w;
            part += __shfl_xor(part, 1);
            part += __shfl_xor(part, 2);
            float a = part * pr;
            float mn = fmaxf(m, a);
            float scale = expf(m - mn);
            float p = expf(a - mn);
            l = l * scale + p;
            acc0.x = acc0.x * scale + p * v0.x;
            acc0.y = acc0.y * scale + p * v0.y;
            acc0.z = acc0.z * scale + p * v0.z;
            acc0.w = acc0.w * scale + p * v0.w;
            acc1.x = acc1.x * scale + p * v1.x;
            acc1.y = acc1.y * scale + p * v1.y;
            acc1.z = acc1.z * scale + p * v1.z;
            acc1.w = acc1.w * scale + p * v1.w;
            m = mn;
        }
    }
    #pragma unroll
    for (int mask = 16; mask <= 32; mask <<= 1) {
        float m_o = __shfl_xor(m, mask);
        float l_o = __shfl_xor(l, mask);
        float4 a0o, a1o;
        a0o.x = __shfl_xor(acc0.x, mask); a0o.y = __shfl_xor(acc0.y, mask);
        a0o.z = __shfl_xor(acc0.z, mask); a0o.w = __shfl_xor(acc0.w, mask);
        a1o.x = __shfl_xor(acc1.x, mask); a1o.y = __shfl_xor(acc1.y, mask);
        a1o.z = __shfl_xor(acc1.z, mask); a1o.w = __shfl_xor(acc1.w, mask);
        float mn = fmaxf(m, m_o);
        float s0 = expf(m - mn), s1 = expf(m_o - mn);
        l = l * s0 + l_o * s1;
        acc0.x = acc0.x * s0 + a0o.x * s1; acc0.y = acc0.y * s0 + a0o.y * s1;
        acc0.z = acc0.z * s0 + a0o.z * s1; acc0.w = acc0.w * s0 + a0o.w * s1;
        acc1.x = acc1.x * s0 + a1o.x * s1; acc1.y = acc1.y * s0 + a1o.y * s1;
        acc1.z = acc1.z * s0 + a1o.z * s1; acc1.w = acc1.w * s0 + a1o.w * s1;
        m = mn;
    }
    float inv = (beg == end) ? 0.f : 1.f / (l + 1e-16f);
    if (group == 0) {
        float* orow = qo + (size_t)d * 128 + gl * 8;
        float4 o0, o1;
        o0.x = gelu_f(acc0.x * inv); o0.y = gelu_f(acc0.y * inv);
        o0.z = gelu_f(acc0.z * inv); o0.w = gelu_f(acc0.w * inv);
        o1.x = gelu_f(acc1.x * inv); o1.y = gelu_f(acc1.y * inv);
        o1.z = gelu_f(acc1.z * inv); o1.w = gelu_f(acc1.w * inv);
        *(float4*)(orow)     = o0;
        *(float4*)(orow + 4) = o1;
    }
}

// ======================= final scoring =======================
__global__ __launch_bounds__(256)
void score_pairs(const int* __restrict__ ic, const int* __restrict__ id,
                 const float* __restrict__ zC, const float* __restrict__ zD,
                 float* __restrict__ out)
{
    int gid = blockIdx.x * 256 + threadIdx.x;
    int p = gid >> 4, lane = gid & 15;
    if (p >= L_CNT) return;
    int c = ic[p], d = id[p];
    float4 a = *(const float4*)(zC + (size_t)c * 64 + lane * 4);
    float4 b = *(const float4*)(zD + (size_t)d * 64 + lane * 4);
    float s = a.x * b.x + a.y * b.y + a.z * b.z + a.w * b.w;
    s += __shfl_down(s, 8, 16);
    s += __shfl_down(s, 4, 16);
    s += __shfl_down(s, 2, 16);
    s += __shfl_down(s, 1, 16);
    if (lane == 0) out[p] = fminf(10.0f, fmaxf(-10.0f, s));
}

extern "C" void kernel_launch(void* const* d_in, const int* in_sizes, int n_in,
                              void* d_out, int out_size, void* d_ws, size_t ws_size,
                              hipStream_t stream)
{
    // Persistent node states live in the emb input buffers (harness restores
    // d_in from pristine copies before every timed launch).
    float* xC = (float*)d_in[0];
    float* xD = (float*)d_in[1];
    const float* kW   = (const float*)d_in[2];
    const float* kb   = (const float*)d_in[3];
    const float* qW   = (const float*)d_in[4];
    const float* qb   = (const float*)d_in[5];
    const float* vW   = (const float*)d_in[6];
    const float* vb   = (const float*)d_in[7];
    const float* aW   = (const float*)d_in[8];
    const float* ab   = (const float*)d_in[9];
    const float* skip = (const float*)d_in[10];
    const float* arel = (const float*)d_in[11];
    const float* mrel = (const float*)d_in[12];
    const float* prel = (const float*)d_in[13];
    const float* outW = (const float*)d_in[14];
    const float* outb = (const float*)d_in[15];
    const int* ei_cd  = (const int*)d_in[16];
    const int* ei_dc  = (const int*)d_in[17];
    const int* eli    = (const int*)d_in[18];

    // ---- workspace: ~38.6M floats + ~1.6M ints ≈ 161 MB ----
    float* ws = (float*)d_ws;
    size_t off = 0;
    float* kv    = ws + off; off += (size_t)NN_ * 256;   // 25.6M  src [k|v]
    float* qo    = ws + off; off += (size_t)NN_ * 128;   // 12.8M  dst q -> gelu(attn out)
    float* Wcat  = ws + off; off += (size_t)4 * WCAT_SZ;
    int* iws = (int*)(ws + off);
    size_t ioff = 0;
    int* rp      = iws + ioff; ioff += 2 * (NN_ + 1);    // row_ptr planes [r]
    int* srcsA   = iws + ioff; ioff += 2 * E_CNT;        // src planes [r]
    int* cnt     = iws + ioff; ioff += 2 * NN_;
    int* cursor  = iws + ioff; ioff += 2 * NN_;
    int* partial = iws + ioff; ioff += 256;
    float* zC = kv;                                      // reuse after edge phases
    float* zD = kv + (size_t)NN_ * 128;

    const int gridM = (NN_ + 127) / 128;          // 782
    const int gE    = (E_CNT + 255) / 256;
    const int gN2   = (2 * NN_ + 255) / 256;
    const int gScan = 98;
    const int gGath = (NN_ + 3) / 4;              // 4 waves/block

    // ---- build CSR for both relations (fused, grid.y = r) ----
    fill0_int<<<gN2, 256, 0, stream>>>(cnt, 2 * NN_);
    count_dst<<<dim3(gE, 2), 256, 0, stream>>>(ei_cd + E_CNT, ei_dc + E_CNT, cnt);
    scan_a<<<dim3(gScan, 2), 256, 0, stream>>>(cnt, rp, partial);
    scan_b<<<2, 128, 0, stream>>>(partial);
    scan_c<<<dim3(gScan, 2), 256, 0, stream>>>(rp, partial, cursor);
    scatter_edges<<<dim3(gE, 2), 256, 0, stream>>>(ei_cd, ei_cd + E_CNT,
                                                   ei_dc, ei_dc + E_CNT, cursor, srcsA);
    int* rp_cd   = rp;
    int* rp_dc   = rp + (NN_ + 1);
    int* srcs_cd = srcsA;
    int* srcs_dc = srcsA + E_CNT;

    // ---- all weight fusion in one launch ----
    fuse_weights<<<dim3(129, 2, 2), 384, 0, stream>>>(qW, qb, kW, kb, vW, vb,
                                                      arel, mrel, Wcat);

    for (int l = 0; l < 2; l++) {
        const float* aWl = aW + (size_t)l * 2 * 128 * 128;
        const float* abl = ab + (size_t)l * 2 * 128;
        float* WcC = Wcat + (size_t)(l * 2 + 0) * WCAT_SZ;
        float* WcD = Wcat + (size_t)(l * 2 + 1) * WCAT_SZ;

        // ---- relation 0: C -> D ----  (dual: kvC y0-1, qD y2)
        gemm2<128, 0><<<dim3(gridM, 3), 256, 0, stream>>>(
            xC, 128, WcC + 128, 384, WcC + 128 * 384 + 128, kv, 256, NC_, nullptr, nullptr,
            2, xD, WcD, WcD + 128 * 384, qo, 128);
        attn_gather<<<gGath, 256, 0, stream>>>(rp_cd, srcs_cd, qo, kv,
                                               prel + (l * 2 + 0) * 4, ND_);  // gelu(outD) in qo

        // kvD from OLD xD (before epilogue D overwrites it)
        gemm2<128, 0><<<dim3(gridM, 2), 256, 0, stream>>>(
            xD, 128, WcD + 128, 384, WcD + 128 * 384 + 128, kv, 256, ND_, nullptr, nullptr,
            -1, nullptr, nullptr, nullptr, nullptr, 0);

        // epilogue D: xD = relu(g*(gelu(outD)@aW_D+ab_D) + (1-g)*xD)
        gemm2<128, 1><<<dim3(gridM, 1), 256, 0, stream>>>(
            qo, 128, aWl + 128 * 128, 128, abl + 128, xD, 128, ND_, xD, skip + l * 2 + 1,
            -1, nullptr, nullptr, nullptr, nullptr, 0);

        // ---- relation 1: D -> C ----
        gemm2<128, 0><<<dim3(gridM, 1), 256, 0, stream>>>(     // qC (old xC)
            xC, 128, WcC, 384, WcC + 128 * 384, qo, 128, NC_, nullptr, nullptr,
            -1, nullptr, nullptr, nullptr, nullptr, 0);
        attn_gather<<<gGath, 256, 0, stream>>>(rp_dc, srcs_dc, qo, kv,
                                               prel + (l * 2 + 1) * 4, NC_);  // gelu(outC) in qo

        // epilogue C
        gemm2<128, 1><<<dim3(gridM, 1), 256, 0, stream>>>(
            qo, 128, aWl, 128, abl, xC, 128, NC_, xC, skip + l * 2 + 0,
            -1, nullptr, nullptr, nullptr, nullptr, 0);
    }

    // final projections z = x @ outW + outb  ([N,128] @ [128,64]), both types dual
    gemm2<64, 0><<<dim3(gridM, 2), 256, 0, stream>>>(
        xC, 128, outW, 64, outb, zC, 64, NC_, nullptr, nullptr,
        1, xD, outW + 128 * 64, outb + 64, zD, 64);

    score_pairs<<<(L_CNT * 16 + 255) / 256, 256, 0, stream>>>(
        eli, eli + L_CNT, zC, zD, (float*)d_out);
}

// Round 9
// 1267.757 us; speedup vs baseline: 1.2441x; 1.1400x over previous
//
#include <hip/hip_runtime.h>
#include <math.h>

#define NC_   100000
#define ND_   100000
#define NN_   100000   // == NC_ == ND_
#define E_CNT 500000
#define L_CNT 100000
#define NH_   4
#define HD_   32
#define WCAT_SZ (129 * 384)

typedef __attribute__((ext_vector_type(8))) short short8;
typedef __attribute__((ext_vector_type(4))) float floatx4;

__device__ __forceinline__ float gelu_f(float x) {
    const float c0 = 0.7978845608028654f; // sqrt(2/pi)
    float x3 = x * x * x;
    return 0.5f * x * (1.0f + tanhf(c0 * (x + 0.044715f * x3)));
}

__device__ __forceinline__ unsigned short bf_rne(float x) {
    unsigned int u = __float_as_uint(x);
    u += 0x7fffu + ((u >> 16) & 1u);
    return (unsigned short)(u >> 16);
}
__device__ __forceinline__ float bf_to_f(unsigned short b) {
    return __uint_as_float(((unsigned int)b) << 16);
}

// ======================= CSR build (both relations fused, grid.y = r) ==========
__global__ __launch_bounds__(256) void fill0_int(int* __restrict__ p, int n) {
    int i = blockIdx.x * 256 + threadIdx.x;
    if (i < n) p[i] = 0;
}

__global__ __launch_bounds__(256) void count_dst(const int* __restrict__ dstA,
                                                 const int* __restrict__ dstB,
                                                 int* __restrict__ cnt) {
    int r = blockIdx.y;
    const int* dst = r ? dstB : dstA;
    int e = blockIdx.x * 256 + threadIdx.x;
    if (e < E_CNT) atomicAdd(&cnt[r * NN_ + dst[e]], 1);
}

__global__ __launch_bounds__(256) void scan_a(const int* __restrict__ cnt,
                                              int* __restrict__ excl,
                                              int* __restrict__ partials) {
    __shared__ int sd[256];
    int r = blockIdx.y;
    cnt += r * NN_; excl += r * (NN_ + 1); partials += r * 128;
    int b = blockIdx.x, t = threadIdx.x;
    int base = b * 1024 + t * 4;
    int v0 = (base + 0 < NN_) ? cnt[base + 0] : 0;
    int v1 = (base + 1 < NN_) ? cnt[base + 1] : 0;
    int v2 = (base + 2 < NN_) ? cnt[base + 2] : 0;
    int v3 = (base + 3 < NN_) ? cnt[base + 3] : 0;
    int tsum = v0 + v1 + v2 + v3;
    sd[t] = tsum; __syncthreads();
    for (int off = 1; off < 256; off <<= 1) {
        int x = (t >= off) ? sd[t - off] : 0;
        __syncthreads();
        sd[t] += x;
        __syncthreads();
    }
    int excl_t = sd[t] - tsum;
    if (t == 255) partials[b] = sd[t];
    int q = excl_t;
    if (base + 0 < NN_) excl[base + 0] = q; q += v0;
    if (base + 1 < NN_) excl[base + 1] = q; q += v1;
    if (base + 2 < NN_) excl[base + 2] = q; q += v2;
    if (base + 3 < NN_) excl[base + 3] = q;
}

__global__ __launch_bounds__(128) void scan_b(int* __restrict__ partials) {
    __shared__ int sd[128];
    partials += blockIdx.x * 128;
    int t = threadIdx.x;
    int orig = (t < 98) ? partials[t] : 0;
    sd[t] = orig; __syncthreads();
    for (int off = 1; off < 128; off <<= 1) {
        int x = (t >= off) ? sd[t - off] : 0;
        __syncthreads();
        sd[t] += x;
        __syncthreads();
    }
    if (t < 98) partials[t] = sd[t] - orig;
}

__global__ __launch_bounds__(256) void scan_c(int* __restrict__ row_ptr,
                                              const int* __restrict__ partials,
                                              int* __restrict__ cursor) {
    int r = blockIdx.y;
    row_ptr += r * (NN_ + 1); partials += r * 128; cursor += r * NN_;
    int b = blockIdx.x, t = threadIdx.x;
    int base = b * 1024 + t * 4;
    int add = partials[b];
    #pragma unroll
    for (int j = 0; j < 4; j++) {
        int i = base + j;
        if (i < NN_) { int v = row_ptr[i] + add; row_ptr[i] = v; cursor[i] = v; }
    }
    if (b == 0 && t == 0) row_ptr[NN_] = E_CNT;
}

__global__ __launch_bounds__(256) void scatter_edges(const int* __restrict__ srcA,
                                                     const int* __restrict__ dstA,
                                                     const int* __restrict__ srcB,
                                                     const int* __restrict__ dstB,
                                                     int* __restrict__ cursor,
                                                     int* __restrict__ srcs) {
    int r = blockIdx.y;
    const int* src = r ? srcB : srcA;
    const int* dst = r ? dstB : dstA;
    cursor += r * NN_; srcs += r * E_CNT;
    int e = blockIdx.x * 256 + threadIdx.x;
    if (e >= E_CNT) return;
    int pos = atomicAdd(&cursor[dst[e]], 1);
    srcs[pos] = src[e];
}

// ======================= weight fusion (both layers in one launch) ==============
__global__ void fuse_weights(const float* __restrict__ qW, const float* __restrict__ qb,
                             const float* __restrict__ kW, const float* __restrict__ kb,
                             const float* __restrict__ vW, const float* __restrict__ vb,
                             const float* __restrict__ arel, const float* __restrict__ mrel,
                             float* __restrict__ WcatAll)
{
    int i  = blockIdx.x;   // 0..128 (128 == bias row)
    int t  = blockIdx.y;
    int lyr = blockIdx.z;
    int oc = threadIdx.x;  // 0..383
    int lt = lyr * 2 + t;
    float* Wcat = WcatAll + (size_t)lt * WCAT_SZ;
    float val;
    if (oc < 128) {
        val = (i < 128) ? qW[(size_t)(lt * 128 + i) * 128 + oc] : qb[lt * 128 + oc];
    } else {
        int which = (oc >= 256);
        int cc = oc - (which ? 256 : 128);
        int h = cc >> 5, e = cc & 31;
        const float* W = which ? vW : kW;
        const float* b = which ? vb : kb;
        const float* R = (which ? mrel : arel) + (size_t)(lt * NH_ + h) * HD_ * HD_ + e;
        float s = 0.f;
        if (i < 128) {
            const float* wrow = W + (size_t)(lt * 128 + i) * 128 + h * 32;
            #pragma unroll
            for (int d2 = 0; d2 < 32; d2++) s += wrow[d2] * R[d2 * 32];
        } else {
            const float* brow = b + lt * 128 + h * 32;
            #pragma unroll
            for (int d2 = 0; d2 < 32; d2++) s += brow[d2] * R[d2 * 32];
        }
        val = s;
    }
    Wcat[(size_t)((i < 128) ? i : 128) * 384 + oc] = val;
}

// ======================= weight 3-term bf16 split ==============================
// In: W[k][n] fp32 (k<128, stride ldw), matStride per blockIdx.y matrix.
// Out: 3 bf16 planes, each [n][128] (B-fragment-friendly), plane stride N*128.
__global__ __launch_bounds__(128)
void split_w(const float* __restrict__ W, int ldw, int matStride,
             unsigned short* __restrict__ out, int N, int outMatStride)
{
    int n = blockIdx.x;
    int mat = blockIdx.y;
    int k = threadIdx.x;           // 0..127
    float x = W[(size_t)mat * matStride + (size_t)k * ldw + n];
    unsigned short b0 = bf_rne(x);
    float x1 = x - bf_to_f(b0);
    unsigned short b1 = bf_rne(x1);
    float x2 = x1 - bf_to_f(b1);
    unsigned short b2 = bf_rne(x2);
    int ps = N * 128;
    unsigned short* o = out + (size_t)mat * outMatStride + (size_t)n * 128 + k;
    o[0] = b0; o[ps] = b1; o[2 * ps] = b2;
}

// ======================= MFMA GEMM via 3-term bf16 split =======================
// C[M,N] = A[M,128] @ B[128,N] + bias, fp32-grade accuracy from 6 bf16 MFMAs
// per tile (products of order >= 2^-16 kept; accumulated low->high in fp32).
// Tile: 64 rows x TN cols, K-slabs of 32, 256 threads (4 waves, 16 rows each).
// A split on the fly into 3 LDS planes [m][k] (stride 40 bf16: 16B-aligned
// frags, <=2-way bank alias). B pre-split globally into [n][k] bf16 planes.
// POST: C = relu(g*v + (1-g)*resid) (resid may alias C). Dual via ySplit.
template<int TN, int POST>
__global__ __launch_bounds__(256)
void gemm_mfma(const float* __restrict__ A, int lda,
               const unsigned short* __restrict__ Bs3, int pstride,
               const float* __restrict__ bias,
               float* __restrict__ C, int ldc, int M,
               const float* __restrict__ resid, const float* __restrict__ skipv,
               int ySplit,
               const float* __restrict__ A2, const unsigned short* __restrict__ Bs32,
               int pstride2, const float* __restrict__ bias2,
               float* __restrict__ C2, int ldc2)
{
    constexpr int CT = TN / 16;
    __shared__ unsigned short Asl[3 * 64 * 40];   // [p][m][k] stride 40
    __shared__ unsigned short Bsl[3 * TN * 40];   // [p][n][k] stride 40
    int by = blockIdx.y;
    if (ySplit >= 0 && by >= ySplit) {
        A = A2; Bs3 = Bs32; pstride = pstride2; bias = bias2; C = C2; ldc = ldc2;
        by -= ySplit;
    }
    int tid  = threadIdx.x;
    int wave = tid >> 6, lane = tid & 63;
    int quad = lane >> 4, l16 = lane & 15;
    int bm = blockIdx.x * 64;
    int bn = by * TN;

    floatx4 acc[CT];
    #pragma unroll
    for (int ct = 0; ct < CT; ct++) acc[ct] = (floatx4){0.f, 0.f, 0.f, 0.f};

    // A staging: thread -> row sm (0..63), 8 k at kq
    int sm = tid >> 2;             // 0..63
    int kq = (tid & 3) * 8;        // 0,8,16,24
    int arow = bm + sm;
    bool aval = arow < M;
    const float* ap = A + (size_t)arow * lda + kq;
    // B staging: thread -> n row sn (0..127), 16 k at kh
    int sn = tid >> 1;             // 0..127
    int kh = (tid & 1) * 16;       // 0 or 16
    const unsigned short* bp = Bs3 + (size_t)(bn + sn) * 128 + kh;

    for (int ks = 0; ks < 128; ks += 32) {
        __syncthreads();
        // ---- stage A: load 8 fp32, split to 3 bf16 planes
        float xv[8];
        if (aval) {
            *(float4*)&xv[0] = *(const float4*)(ap + ks);
            *(float4*)&xv[4] = *(const float4*)(ap + ks + 4);
        } else {
            #pragma unroll
            for (int i = 0; i < 8; i++) xv[i] = 0.f;
        }
        #pragma unroll
        for (int i = 0; i < 8; i += 2) {
            float xa = xv[i], xb = xv[i + 1];
            unsigned short a0 = bf_rne(xa); float ra = xa - bf_to_f(a0);
            unsigned short a1 = bf_rne(ra); float ra2 = ra - bf_to_f(a1);
            unsigned short a2 = bf_rne(ra2);
            unsigned short c0 = bf_rne(xb); float rb = xb - bf_to_f(c0);
            unsigned short c1 = bf_rne(rb); float rb2 = rb - bf_to_f(c1);
            unsigned short c2 = bf_rne(rb2);
            int idx = sm * 40 + kq + i;
            *(unsigned int*)&Asl[idx]            = (unsigned)a0 | ((unsigned)c0 << 16);
            *(unsigned int*)&Asl[2560 + idx]     = (unsigned)a1 | ((unsigned)c1 << 16);
            *(unsigned int*)&Asl[5120 + idx]     = (unsigned)a2 | ((unsigned)c2 << 16);
        }
        // ---- stage B: copy pre-split planes (16 bf16 per plane per thread)
        if (sn < TN) {
            #pragma unroll
            for (int p = 0; p < 3; p++) {
                uint4 v0 = *(const uint4*)(bp + (size_t)p * pstride + ks);
                uint4 v1 = *(const uint4*)(bp + (size_t)p * pstride + ks + 8);
                int bidx = p * (TN * 40) + sn * 40 + kh;
                *(uint4*)&Bsl[bidx]     = v0;
                *(uint4*)&Bsl[bidx + 8] = v1;
            }
        }
        __syncthreads();
        // ---- fragments + MFMA (low-order products first)
        int am = wave * 16 + l16;
        short8 af0 = *(const short8*)&Asl[am * 40 + quad * 8];
        short8 af1 = *(const short8*)&Asl[2560 + am * 40 + quad * 8];
        short8 af2 = *(const short8*)&Asl[5120 + am * 40 + quad * 8];
        #pragma unroll
        for (int ct = 0; ct < CT; ct++) {
            int bnn = (ct * 16 + l16) * 40 + quad * 8;
            short8 bf0 = *(const short8*)&Bsl[bnn];
            short8 bf1 = *(const short8*)&Bsl[TN * 40 + bnn];
            short8 bf2 = *(const short8*)&Bsl[2 * TN * 40 + bnn];
            acc[ct] = __builtin_amdgcn_mfma_f32_16x16x32_bf16(af0, bf2, acc[ct], 0, 0, 0);
            acc[ct] = __builtin_amdgcn_mfma_f32_16x16x32_bf16(af1, bf1, acc[ct], 0, 0, 0);
            acc[ct] = __builtin_amdgcn_mfma_f32_16x16x32_bf16(af2, bf0, acc[ct], 0, 0, 0);
            acc[ct] = __builtin_amdgcn_mfma_f32_16x16x32_bf16(af0, bf1, acc[ct], 0, 0, 0);
            acc[ct] = __builtin_amdgcn_mfma_f32_16x16x32_bf16(af1, bf0, acc[ct], 0, 0, 0);
            acc[ct] = __builtin_amdgcn_mfma_f32_16x16x32_bf16(af0, bf0, acc[ct], 0, 0, 0);
        }
    }

    // ---- epilogue: C/D layout col=lane&15, row=quad*4+reg
    float g = 0.f, omg = 0.f;
    if (POST) { float sv = skipv[0]; g = 1.0f / (1.0f + expf(-sv)); omg = 1.0f - g; }
    #pragma unroll
    for (int ct = 0; ct < CT; ct++) {
        int col = bn + ct * 16 + l16;
        float bv = bias[col];
        #pragma unroll
        for (int i = 0; i < 4; i++) {
            int row = bm + wave * 16 + quad * 4 + i;
            if (row < M) {
                float v = acc[ct][i] + bv;
                if (POST) {
                    float r = resid[(size_t)row * ldc + col];
                    v = fmaxf(g * v + omg * r, 0.f);
                }
                C[(size_t)row * ldc + col] = v;
            }
        }
    }
}

// ======================= fused attention gather (4 edges in flight) ============
__global__ __launch_bounds__(256)
void attn_gather(const int* __restrict__ row_ptr, const int* __restrict__ srcs,
                 float* __restrict__ qo, const float* __restrict__ kv,
                 const float* __restrict__ prel, int ndst)
{
    int wave = (blockIdx.x * 256 + threadIdx.x) >> 6;
    int lane = threadIdx.x & 63;
    if (wave >= ndst) return;
    int d = wave;
    int gl = lane & 15;
    int group = lane >> 4;
    int h = gl >> 2;
    float pr = prel[h] * 0.17677669529663687f;  // prel / sqrt(32)
    int beg = row_ptr[d], end = row_ptr[d + 1];
    const float* qrow = qo + (size_t)d * 128 + gl * 8;
    float4 q0 = *(const float4*)(qrow);
    float4 q1 = *(const float4*)(qrow + 4);
    float m = -1.0e30f, l = 0.f;
    float4 acc0 = make_float4(0.f,0.f,0.f,0.f), acc1 = acc0;
    int nt = (end - beg + 3) >> 2;
    for (int t = 0; t < nt; t++) {
        int i = beg + (t << 2) + group;
        if (i < end) {
            int s = srcs[i];
            const float* row = kv + (size_t)s * 256 + gl * 8;
            float4 k0 = *(const float4*)(row);
            float4 k1 = *(const float4*)(row + 4);
            float4 v0 = *(const float4*)(row + 128);
            float4 v1 = *(const float4*)(row + 132);
            float part = q0.x*k0.x + q0.y*k0.y + q0.z*k0.z + q0.w*k0.w
                       + q1.x*k1.x + q1.y*k1.y + q1.z*k1.z + q1.w*k1.w;
            part += __shfl_xor(part, 1);
            part += __shfl_xor(part, 2);
            float a = part * pr;
            float mn = fmaxf(m, a);
            float scale = expf(m - mn);
            float p = expf(a - mn);
            l = l * scale + p;
            acc0.x = acc0.x * scale + p * v0.x;
            acc0.y = acc0.y * scale + p * v0.y;
            acc0.z = acc0.z * scale + p * v0.z;
            acc0.w = acc0.w * scale + p * v0.w;
            acc1.x = acc1.x * scale + p * v1.x;
            acc1.y = acc1.y * scale + p * v1.y;
            acc1.z = acc1.z * scale + p * v1.z;
            acc1.w = acc1.w * scale + p * v1.w;
            m = mn;
        }
    }
    #pragma unroll
    for (int mask = 16; mask <= 32; mask <<= 1) {
        float m_o = __shfl_xor(m, mask);
        float l_o = __shfl_xor(l, mask);
        float4 a0o, a1o;
        a0o.x = __shfl_xor(acc0.x, mask); a0o.y = __shfl_xor(acc0.y, mask);
        a0o.z = __shfl_xor(acc0.z, mask); a0o.w = __shfl_xor(acc0.w, mask);
        a1o.x = __shfl_xor(acc1.x, mask); a1o.y = __shfl_xor(acc1.y, mask);
        a1o.z = __shfl_xor(acc1.z, mask); a1o.w = __shfl_xor(acc1.w, mask);
        float mn = fmaxf(m, m_o);
        float s0 = expf(m - mn), s1 = expf(m_o - mn);
        l = l * s0 + l_o * s1;
        acc0.x = acc0.x * s0 + a0o.x * s1; acc0.y = acc0.y * s0 + a0o.y * s1;
        acc0.z = acc0.z * s0 + a0o.z * s1; acc0.w = acc0.w * s0 + a0o.w * s1;
        acc1.x = acc1.x * s0 + a1o.x * s1; acc1.y = acc1.y * s0 + a1o.y * s1;
        acc1.z = acc1.z * s0 + a1o.z * s1; acc1.w = acc1.w * s0 + a1o.w * s1;
        m = mn;
    }
    float inv = (beg == end) ? 0.f : 1.f / (l + 1e-16f);
    if (group == 0) {
        float* orow = qo + (size_t)d * 128 + gl * 8;
        float4 o0, o1;
        o0.x = gelu_f(acc0.x * inv); o0.y = gelu_f(acc0.y * inv);
        o0.z = gelu_f(acc0.z * inv); o0.w = gelu_f(acc0.w * inv);
        o1.x = gelu_f(acc1.x * inv); o1.y = gelu_f(acc1.y * inv);
        o1.z = gelu_f(acc1.z * inv); o1.w = gelu_f(acc1.w * inv);
        *(float4*)(orow)     = o0;
        *(float4*)(orow + 4) = o1;
    }
}

// ======================= final scoring =======================
__global__ __launch_bounds__(256)
void score_pairs(const int* __restrict__ ic, const int* __restrict__ id,
                 const float* __restrict__ zC, const float* __restrict__ zD,
                 float* __restrict__ out)
{
    int gid = blockIdx.x * 256 + threadIdx.x;
    int p = gid >> 4, lane = gid & 15;
    if (p >= L_CNT) return;
    int c = ic[p], d = id[p];
    float4 a = *(const float4*)(zC + (size_t)c * 64 + lane * 4);
    float4 b = *(const float4*)(zD + (size_t)d * 64 + lane * 4);
    float s = a.x * b.x + a.y * b.y + a.z * b.z + a.w * b.w;
    s += __shfl_down(s, 8, 16);
    s += __shfl_down(s, 4, 16);
    s += __shfl_down(s, 2, 16);
    s += __shfl_down(s, 1, 16);
    if (lane == 0) out[p] = fminf(10.0f, fmaxf(-10.0f, s));
}

extern "C" void kernel_launch(void* const* d_in, const int* in_sizes, int n_in,
                              void* d_out, int out_size, void* d_ws, size_t ws_size,
                              hipStream_t stream)
{
    float* xC = (float*)d_in[0];
    float* xD = (float*)d_in[1];
    const float* kW   = (const float*)d_in[2];
    const float* kb   = (const float*)d_in[3];
    const float* qW   = (const float*)d_in[4];
    const float* qb   = (const float*)d_in[5];
    const float* vW   = (const float*)d_in[6];
    const float* vb   = (const float*)d_in[7];
    const float* aW   = (const float*)d_in[8];
    const float* ab   = (const float*)d_in[9];
    const float* skip = (const float*)d_in[10];
    const float* arel = (const float*)d_in[11];
    const float* mrel = (const float*)d_in[12];
    const float* prel = (const float*)d_in[13];
    const float* outW = (const float*)d_in[14];
    const float* outb = (const float*)d_in[15];
    const int* ei_cd  = (const int*)d_in[16];
    const int* ei_dc  = (const int*)d_in[17];
    const int* eli    = (const int*)d_in[18];

    // ---- workspace ≈ 163 MB ----
    float* ws = (float*)d_ws;
    size_t off = 0;
    float* kv    = ws + off; off += (size_t)NN_ * 256;   // src [k|v]
    float* qo    = ws + off; off += (size_t)NN_ * 128;   // dst q -> gelu(attn out)
    float* Wcat  = ws + off; off += (size_t)4 * WCAT_SZ;
    unsigned short* WsCat = (unsigned short*)(ws + off); off += (4 * 3 * 384 * 128) / 2;
    unsigned short* aWs   = (unsigned short*)(ws + off); off += (4 * 3 * 128 * 128) / 2;
    unsigned short* outWs = (unsigned short*)(ws + off); off += (2 * 3 * 64 * 128) / 2;
    int* iws = (int*)(ws + off);
    size_t ioff = 0;
    int* rp      = iws + ioff; ioff += 2 * (NN_ + 1);
    int* srcsA   = iws + ioff; ioff += 2 * E_CNT;
    int* cnt     = iws + ioff; ioff += 2 * NN_;
    int* cursor  = iws + ioff; ioff += 2 * NN_;
    int* partial = iws + ioff; ioff += 256;
    float* zC = kv;
    float* zD = kv + (size_t)NN_ * 128;

    const int gridM = (NN_ + 63) / 64;            // 1563
    const int gE    = (E_CNT + 255) / 256;
    const int gN2   = (2 * NN_ + 255) / 256;
    const int gScan = 98;
    const int gGath = (NN_ + 3) / 4;

    // ---- CSR for both relations ----
    fill0_int<<<gN2, 256, 0, stream>>>(cnt, 2 * NN_);
    count_dst<<<dim3(gE, 2), 256, 0, stream>>>(ei_cd + E_CNT, ei_dc + E_CNT, cnt);
    scan_a<<<dim3(gScan, 2), 256, 0, stream>>>(cnt, rp, partial);
    scan_b<<<2, 128, 0, stream>>>(partial);
    scan_c<<<dim3(gScan, 2), 256, 0, stream>>>(rp, partial, cursor);
    scatter_edges<<<dim3(gE, 2), 256, 0, stream>>>(ei_cd, ei_cd + E_CNT,
                                                   ei_dc, ei_dc + E_CNT, cursor, srcsA);
    int* rp_cd   = rp;
    int* rp_dc   = rp + (NN_ + 1);
    int* srcs_cd = srcsA;
    int* srcs_dc = srcsA + E_CNT;

    // ---- weight fusion + bf16 3-term splits ----
    fuse_weights<<<dim3(129, 2, 2), 384, 0, stream>>>(qW, qb, kW, kb, vW, vb,
                                                      arel, mrel, Wcat);
    split_w<<<dim3(384, 4), 128, 0, stream>>>(Wcat, 384, WCAT_SZ, WsCat, 384, 3 * 384 * 128);
    split_w<<<dim3(128, 4), 128, 0, stream>>>(aW, 128, 128 * 128, aWs, 128, 3 * 128 * 128);
    split_w<<<dim3(64, 2), 128, 0, stream>>>(outW, 64, 128 * 64, outWs, 64, 3 * 64 * 128);

    const int PS_CAT = 384 * 128;   // plane strides
    const int PS_AW  = 128 * 128;
    const int PS_OW  = 64 * 128;

    for (int l = 0; l < 2; l++) {
        const float* abl = ab + (size_t)l * 2 * 128;
        float* WcC = Wcat + (size_t)(l * 2 + 0) * WCAT_SZ;
        float* WcD = Wcat + (size_t)(l * 2 + 1) * WCAT_SZ;
        const unsigned short* WsC = WsCat + (size_t)(l * 2 + 0) * 3 * PS_CAT;
        const unsigned short* WsD = WsCat + (size_t)(l * 2 + 1) * 3 * PS_CAT;
        const unsigned short* aWsD = aWs + (size_t)(l * 2 + 1) * 3 * PS_AW;
        const unsigned short* aWsC = aWs + (size_t)(l * 2 + 0) * 3 * PS_AW;

        // ---- relation 0: C -> D ----  dual: y0-1 kvC, y2 qD
        gemm_mfma<128, 0><<<dim3(gridM, 3), 256, 0, stream>>>(
            xC, 128, WsC + 128 * 128, PS_CAT, WcC + 128 * 384 + 128, kv, 256, NC_,
            nullptr, nullptr,
            2, xD, WsD, PS_CAT, WcD + 128 * 384, qo, 128);
        attn_gather<<<gGath, 256, 0, stream>>>(rp_cd, srcs_cd, qo, kv,
                                               prel + (l * 2 + 0) * 4, ND_);

        // kvD from OLD xD
        gemm_mfma<128, 0><<<dim3(gridM, 2), 256, 0, stream>>>(
            xD, 128, WsD + 128 * 128, PS_CAT, WcD + 128 * 384 + 128, kv, 256, ND_,
            nullptr, nullptr, -1, nullptr, nullptr, 0, nullptr, nullptr, 0);

        // epilogue D
        gemm_mfma<128, 1><<<dim3(gridM, 1), 256, 0, stream>>>(
            qo, 128, aWsD, PS_AW, abl + 128, xD, 128, ND_,
            xD, skip + l * 2 + 1, -1, nullptr, nullptr, 0, nullptr, nullptr, 0);

        // ---- relation 1: D -> C ----
        gemm_mfma<128, 0><<<dim3(gridM, 1), 256, 0, stream>>>(
            xC, 128, WsC, PS_CAT, WcC + 128 * 384, qo, 128, NC_,
            nullptr, nullptr, -1, nullptr, nullptr, 0, nullptr, nullptr, 0);
        attn_gather<<<gGath, 256, 0, stream>>>(rp_dc, srcs_dc, qo, kv,
                                               prel + (l * 2 + 1) * 4, NC_);

        // epilogue C
        gemm_mfma<128, 1><<<dim3(gridM, 1), 256, 0, stream>>>(
            qo, 128, aWsC, PS_AW, abl, xC, 128, NC_,
            xC, skip + l * 2 + 0, -1, nullptr, nullptr, 0, nullptr, nullptr, 0);
    }

    // final projections z = x @ outW + outb, both types dual
    gemm_mfma<64, 0><<<dim3(gridM, 2), 256, 0, stream>>>(
        xC, 128, outWs, PS_OW, outb, zC, 64, NC_, nullptr, nullptr,
        1, xD, outWs + 3 * PS_OW, PS_OW, outb + 64, zD, 64);

    score_pairs<<<(L_CNT * 16 + 255) / 256, 256, 0, stream>>>(
        eli, eli + L_CNT, zC, zD, (float*)d_out);
}